// Round 6
// baseline (434.278 us; speedup 1.0000x reference)
//
#include <hip/hip_runtime.h>
#include <hip/hip_bf16.h>
#include <math.h>

// MotionNet: PointNet++-style 2-level SA.  B=32, L=16, N=512.
// M = B*npoint*nsample = 131072 for all four conv layers.
//
// R6: FPS step loop minimized — per-p body is distance+fmin only (9 insts),
// per-lane max via depth-3 fmax tree, 6-stage DPP max on the spine, and the
// winner's index/coords resolved OFF the spine (equality-select vs `local`,
// descending p => first-max semantics preserved), extracted via ballot-ctz +
// readlane.  Shift kernels folded into the FPS prologue (identical
// arithmetic).  Convs: MFMA bf16 split-precision, LDS-staged fragment-major
// W, fused BN stats (R4/R5).  Exactness discipline unchanged.

#define BATCH 32
#define MCOLS 131072
#define CGRID 2048            // MCOLS / 64 conv blocks

typedef __attribute__((ext_vector_type(8))) short short8;
typedef __attribute__((ext_vector_type(4))) short short4v;
typedef __attribute__((ext_vector_type(4))) float f32x4;

__device__ __forceinline__ float b2f(short s) {
    return __uint_as_float(((unsigned)(unsigned short)s) << 16);
}
__device__ __forceinline__ short f2b(float f) {
    __hip_bfloat16 h = __float2bfloat16(f);
    return (short)__builtin_bit_cast(unsigned short, h);
}
__device__ __forceinline__ float dpp_row16_sum(float v) {
    int x;
    x = __builtin_amdgcn_update_dpp(0, __float_as_int(v), 0x111, 0xf, 0xf, true);
    v += __int_as_float(x);
    x = __builtin_amdgcn_update_dpp(0, __float_as_int(v), 0x112, 0xf, 0xf, true);
    v += __int_as_float(x);
    x = __builtin_amdgcn_update_dpp(0, __float_as_int(v), 0x114, 0xf, 0xf, true);
    v += __int_as_float(x);
    x = __builtin_amdgcn_update_dpp(0, __float_as_int(v), 0x118, 0xf, 0xf, true);
    v += __int_as_float(x);
    return v;
}
template<int C>
__device__ __forceinline__ float dpp_max(float v) {
    int x = __builtin_amdgcn_update_dpp(0, __float_as_int(v), C, 0xf, 0xf, true);
    return fmaxf(v, __int_as_float(x));
}
__device__ __forceinline__ float readlane_f(float v, int lane) {
    return __int_as_float(__builtin_amdgcn_readlane(__float_as_int(v), lane));
}

// ---------------------------------------------------------------- weight prep
// w (O,C) f32 -> hi/lo packed fragment-major, zero-padded cols C..CK-1.
__global__ void prep_w(const float* __restrict__ w, int O, int C, int CK,
                       short* __restrict__ hi, short* __restrict__ lo) {
    int t = blockIdx.x * 256 + threadIdx.x;
    if (t >= O * CK) return;
    int o = t / CK, c = t % CK;
    float f = (c < C) ? w[o * C + c] : 0.f;
    short h = f2b(f);
    float fh = b2f(h);
    int NT = O >> 4;
    int ot = o >> 4, l15 = o & 15;
    int kc = c >> 5, quad = (c & 31) >> 3, j = c & 7;
    size_t idx = (((size_t)kc * NT + ot) * 64 + quad * 16 + l15) * 8 + j;
    hi[idx] = h;
    lo[idx] = f2b(f - fh);
}

// ---------------------------------------------------------------- FPS
// One wave per batch.  Prologue computes the shifted query set (exact
// shift_kernel arithmetic) into LDS.  Lane-major candidates (j = lane*P+p):
// first-max == lowest winner lane, then lowest p.  Spine: dist+fmin ->
// fmax tree -> 6x DPP max -> readlane -> ballot -> ctz -> readlane coords.
template<int N, int NPOINT>
__global__ __launch_bounds__(64) void fps_kernel(const float* __restrict__ src,
                                                 float* __restrict__ qsel) {
    int b = blockIdx.x;
    int lane = threadIdx.x;
    int l = b & 15;
    constexpr int P = N / 64;
    __shared__ float4 qp[N];
    __shared__ int sel[NPOINT];
    // ---- fused shift: q[b] = shift(src)[b], identical arithmetic to R5 ----
    if (l < 15) {
        const float* s = src + (size_t)(b + 1) * N * 3;
        for (int j = lane; j < N; j += 64)
            qp[j] = make_float4(s[j * 3 + 0], s[j * 3 + 1], s[j * 3 + 2], 0.f);
    } else {
        int g0 = b - 15;
        for (int j = lane; j < N; j += 64) {
            float v[3];
#pragma unroll
            for (int c = 0; c < 3; ++c) {
                float acc = 0.f;
                for (int i = 0; i < 15; ++i) {
                    float d = __fsub_rn(src[((size_t)(g0 + i + 1) * N + j) * 3 + c],
                                        src[((size_t)(g0 + i) * N + j) * 3 + c]);
                    acc = __fadd_rn(acc, d);
                }
                v[c] = __fadd_rn(src[((size_t)b * N + j) * 3 + c], __fdiv_rn(acc, 15.f));
            }
            qp[j] = make_float4(v[0], v[1], v[2], 0.f);
        }
    }
    if (lane == 0) sel[0] = 0;
    __syncthreads();
    float px[P], py[P], pz[P], mind[P];
#pragma unroll
    for (int p = 0; p < P; ++p) {
        float4 v = qp[lane * P + p];
        px[p] = v.x; py[p] = v.y; pz[p] = v.z;
        mind[p] = 1e10f;
    }
    float4 L0 = qp[0];
    float lx = L0.x, ly = L0.y, lz = L0.z;
    for (int s = 1; s < NPOINT; ++s) {
        float mn[P];
#pragma unroll
        for (int p = 0; p < P; ++p) {
            float dx = __fsub_rn(px[p], lx);
            float dy = __fsub_rn(py[p], ly);
            float dz = __fsub_rn(pz[p], lz);
            float d = __fadd_rn(__fadd_rn(__fmul_rn(dx, dx), __fmul_rn(dy, dy)),
                                __fmul_rn(dz, dz));
            float m2 = fminf(mind[p], d);
            mind[p] = m2;
            mn[p] = m2;
        }
        // per-lane max, log-depth tree (spine)
        float t[P];
#pragma unroll
        for (int p = 0; p < P; ++p) t[p] = mn[p];
#pragma unroll
        for (int w = P / 2; w >= 1; w >>= 1)
#pragma unroll
            for (int p = 0; p < w; ++p) t[p] = fmaxf(t[p], t[p + w]);
        float local = t[0];
        // 64-lane max (spine)
        float m = local;
        m = dpp_max<0x111>(m);
        m = dpp_max<0x112>(m);
        m = dpp_max<0x114>(m);
        m = dpp_max<0x118>(m);
        m = dpp_max<0x142>(m);
        m = dpp_max<0x143>(m);
        float maxd = readlane_f(m, 63);
        // off-spine: winner-lane-local index + coords (descending p => first p)
        int enc = 0;
        float bx = px[0], by = py[0], bz = pz[0];
#pragma unroll
        for (int p = P - 1; p >= 1; --p) {
            bool e = (mn[p] == local);
            enc = e ? p : enc;
            bx = e ? px[p] : bx;
            by = e ? py[p] : by;
            bz = e ? pz[p] : bz;
        }
        bool e0 = (mn[0] == local);
        enc = e0 ? 0 : enc;
        bx = e0 ? px[0] : bx;
        by = e0 ? py[0] : by;
        bz = e0 ? pz[0] : bz;
        unsigned long long msk = __ballot(local == maxd);
        int winner = (int)__builtin_ctzll(msk);
        int last = winner * P + __builtin_amdgcn_readlane(enc, winner);
        lx = readlane_f(bx, winner);
        ly = readlane_f(by, winner);
        lz = readlane_f(bz, winner);
        if (lane == 0) sel[s] = last;
    }
    __syncthreads();
    for (int i = lane; i < NPOINT; i += 64) {
        float4 Pt = qp[sel[i]];
        size_t o = ((size_t)b * NPOINT + i) * 3;
        qsel[o + 0] = Pt.x;
        qsel[o + 1] = Pt.y;
        qsel[o + 2] = Pt.z;
    }
}

// ---------------------------------------------------------------- ball query
template<int N, int NPOINT, int NS, int CF, int CK>
__global__ __launch_bounds__(256) void ballq_kernel(
        const float* __restrict__ xyz,    // (B,N,3)
        const float* __restrict__ qpts,   // (B,NPOINT,3)
        const float* __restrict__ feats,  // (B,N,CF)
        float r2, float radius,
        short* __restrict__ X, float* __restrict__ gate) {
    static_assert((NS & (NS - 1)) == 0, "NS pow2");
    int lane = threadIdx.x & 63;
    int wib = threadIdx.x >> 6;
    int wid = blockIdx.x * 4 + wib;
    int b = wid / NPOINT;
    int i = wid % NPOINT;
    const float* qp = qpts + ((size_t)b * NPOINT + i) * 3;
    float qx = qp[0], qy = qp[1], qz = qp[2];
    __shared__ int gsh[4][NS];
    int* gidx = gsh[wib];
    int taken = 0, first = 0;
    bool any = false;
#pragma unroll
    for (int base = 0; base < N; base += 64) {
        int j = base + lane;
        const float* p = xyz + ((size_t)b * N + j) * 3;
        float dx = __fsub_rn(qx, p[0]);
        float dy = __fsub_rn(qy, p[1]);
        float dz = __fsub_rn(qz, p[2]);
        float d2 = __fadd_rn(__fadd_rn(__fmul_rn(dx, dx), __fmul_rn(dy, dy)),
                             __fmul_rn(dz, dz));
        bool in = d2 < r2;
        unsigned long long mk = __ballot(in);
        if (!any && mk) { first = base + __builtin_ctzll(mk); any = true; }
        int cb = __builtin_popcountll(mk & ((1ull << lane) - 1ull));
        int slot = taken + cb;
        if (in && slot < NS) gidx[slot] = j;
        taken += (int)__builtin_popcountll(mk);
    }
    if (taken < NS) {
        for (int s = taken + lane; s < NS; s += 64) gidx[s] = any ? first : 0;
    }
    __syncthreads();
    int m0 = (b * NPOINT + i) * NS;
    if (lane < NS) {
        int g = gidx[lane];
        const float* p = xyz + ((size_t)b * N + g) * 3;
        float dx = (p[0] - qx) / radius;
        float dy = (p[1] - qy) / radius;
        float dz = (p[2] - qz) / radius;
        float dist = sqrtf(dx * dx + dy * dy + dz * dz);
        gate[m0 + lane] = 1.f / (1.f + expf(-dist));
    }
    for (int e = lane; e < NS * CK; e += 64) {
        int s = e / CK;
        int c = e % CK;
        int g = gidx[s];
        float v;
        if (c < 3) {
            float qc = (c == 0) ? qx : ((c == 1) ? qy : qz);
            v = (xyz[((size_t)b * N + g) * 3 + c] - qc) / radius;
        } else if (c < 3 + CF) {
            v = feats[((size_t)b * N + g) * CF + (c - 3)];
        } else {
            v = 0.f;
        }
        X[(size_t)(m0 + s) * CK + c] = f2b(v);
    }
}

// ---------------------------------------------------------------- MFMA conv
// X (M,CK) bf16 -> Y (M,O) bf16.  W chunks staged in LDS per k-step
// (fragment-major, coalesced, shared by all 4 waves).  Waves split O.
// Fused BN stats: f32 acc sums -> DPP row16 reduce -> per-block partials.
template<int CK, int O, bool AFF>
__global__ __launch_bounds__(256, 3) void mfma_conv(
        const short* __restrict__ X, const short* __restrict__ Whi,
        const short* __restrict__ Wlo, const float* __restrict__ ss,
        short* __restrict__ Y, float* __restrict__ pS, float* __restrict__ pS2) {
    constexpr int KC = CK / 32;
    constexpr int NT = O / 16;
    constexpr int OW = NT / 4;
    constexpr int LR = CK + 8;
    constexpr int CB = CK / 8;
    __shared__ __align__(16) short xs[64 * LR];
    __shared__ __align__(16) short wh[NT * 512];
    __shared__ __align__(16) short wl[NT * 512];
    __shared__ float ssl[AFF ? 2 * CK : 1];
    __shared__ float sblk[O], s2blk[O];
    int tid = threadIdx.x;
    int m0 = blockIdx.x * 64;

    if constexpr (AFF) {
        for (int i = tid; i < 2 * CK; i += 256) ssl[i] = ss[i];
        __syncthreads();
    }
    for (int idx = tid; idx < 64 * CB; idx += 256) {
        int r = idx / CB;
        int col = (idx % CB) * 8;
        short8 v = *(const short8*)(X + (size_t)(m0 + r) * CK + col);
        if constexpr (AFF) {
#pragma unroll
            for (int i = 0; i < 8; ++i) {
                float f = b2f(v[i]);
                f = fmaf(f, ssl[col + i], ssl[CK + col + i]);
                f = f > 0.f ? f : 0.2f * f;
                v[i] = f2b(f);
            }
        }
        *(short8*)(xs + r * LR + col) = v;
    }

    int lane = tid & 63;
    int wave = tid >> 6;
    int l15 = lane & 15;
    int quad = lane >> 4;
    int obase = wave * OW * 16;

    f32x4 acc[4][OW];
#pragma unroll
    for (int mt = 0; mt < 4; ++mt)
#pragma unroll
        for (int ot = 0; ot < OW; ++ot) acc[mt][ot] = (f32x4){0.f, 0.f, 0.f, 0.f};

    for (int kc = 0; kc < KC; ++kc) {
        __syncthreads();
        {
            const short8* gH = (const short8*)Whi + (size_t)kc * NT * 64;
            const short8* gL = (const short8*)Wlo + (size_t)kc * NT * 64;
            short8* lH = (short8*)wh;
            short8* lL = (short8*)wl;
            for (int i = tid; i < NT * 64; i += 256) { lH[i] = gH[i]; lL[i] = gL[i]; }
        }
        __syncthreads();
        short8 bf[4];
#pragma unroll
        for (int mt = 0; mt < 4; ++mt)
            bf[mt] = *(const short8*)(xs + (mt * 16 + l15) * LR + kc * 32 + quad * 8);
#pragma unroll
        for (int ot = 0; ot < OW; ++ot) {
            short8 ah = ((const short8*)wh)[(wave * OW + ot) * 64 + lane];
            short8 al = ((const short8*)wl)[(wave * OW + ot) * 64 + lane];
#pragma unroll
            for (int mt = 0; mt < 4; ++mt) {
                acc[mt][ot] = __builtin_amdgcn_mfma_f32_16x16x32_bf16(ah, bf[mt], acc[mt][ot], 0, 0, 0);
                acc[mt][ot] = __builtin_amdgcn_mfma_f32_16x16x32_bf16(al, bf[mt], acc[mt][ot], 0, 0, 0);
            }
        }
    }

#pragma unroll
    for (int mt = 0; mt < 4; ++mt) {
        size_t ybase = (size_t)(m0 + mt * 16 + l15) * O + obase + quad * 4;
#pragma unroll
        for (int ot = 0; ot < OW; ++ot) {
            short4v pk;
#pragma unroll
            for (int r4 = 0; r4 < 4; ++r4) pk[r4] = f2b(acc[mt][ot][r4]);
            *(short4v*)(Y + ybase + ot * 16) = pk;
        }
    }
#pragma unroll
    for (int ot = 0; ot < OW; ++ot) {
#pragma unroll
        for (int r4 = 0; r4 < 4; ++r4) {
            float s = 0.f, s2 = 0.f;
#pragma unroll
            for (int mt = 0; mt < 4; ++mt) {
                float v = acc[mt][ot][r4];
                s += v;
                s2 = fmaf(v, v, s2);
            }
            s = dpp_row16_sum(s);
            s2 = dpp_row16_sum(s2);
            if (l15 == 15) {
                int o = obase + ot * 16 + quad * 4 + r4;
                sblk[o] = s;
                s2blk[o] = s2;
            }
        }
    }
    __syncthreads();
    for (int o = tid; o < O; o += 256) {
        pS [(size_t)o * CGRID + blockIdx.x] = sblk[o];
        pS2[(size_t)o * CGRID + blockIdx.x] = s2blk[o];
    }
}

// ---------------------------------------------------------------- BN finalize
template<int O>
__global__ __launch_bounds__(256) void stats_fin(
        const float* __restrict__ pS, const float* __restrict__ pS2,
        const float* __restrict__ gm, const float* __restrict__ bt,
        float* __restrict__ norm) {
    int o = blockIdx.x;
    float s = 0.f, s2 = 0.f;
    for (int p = threadIdx.x; p < CGRID; p += 256) {
        s += pS[(size_t)o * CGRID + p];
        s2 += pS2[(size_t)o * CGRID + p];
    }
#pragma unroll
    for (int off = 32; off >= 1; off >>= 1) {
        s  += __shfl_xor(s,  off, 64);
        s2 += __shfl_xor(s2, off, 64);
    }
    __shared__ float sh[8];
    int wid = threadIdx.x >> 6;
    if ((threadIdx.x & 63) == 0) { sh[wid] = s; sh[4 + wid] = s2; }
    __syncthreads();
    if (threadIdx.x == 0) {
        float S  = sh[0] + sh[1] + sh[2] + sh[3];
        float S2 = sh[4] + sh[5] + sh[6] + sh[7];
        const float invM = 1.f / (float)MCOLS;
        float mu = S * invM;
        float var = S2 * invM - mu * mu;
        float sc = gm[o] * rsqrtf(var + 1e-5f);
        norm[o] = sc;
        norm[O + o] = bt[o] - mu * sc;
    }
}

// ---------------------------------------------------------------- pool 1
template<int NS, int NPOINT, int O>
__global__ __launch_bounds__(256) void pool1_kernel(
        const short* __restrict__ Y, const float* __restrict__ norm,
        const float* __restrict__ gate, float* __restrict__ out) {
    int t = blockIdx.x * 256 + threadIdx.x;
    int o = t % O;
    int n = (t / O) % NPOINT;
    int b = t / (O * NPOINT);
    int m0 = (b * NPOINT + n) * NS;
    float sc = norm[o], sf = norm[O + o];
    float best = -INFINITY;
#pragma unroll
    for (int k = 0; k < NS; ++k) {
        float v = fmaf(b2f(Y[(size_t)(m0 + k) * O + o]), sc, sf);
        v = v > 0.f ? v : 0.2f * v;
        best = fmaxf(best, gate[m0 + k] * v);
    }
    out[t] = best;
}

// ---------------------------------------------------------------- pool 2
__global__ __launch_bounds__(256) void pool2_kernel(
        const short* __restrict__ Y, const float* __restrict__ norm,
        const float* __restrict__ gate, float* __restrict__ out) {
    constexpr int NS = 32, NPOINT = 128, O = 256;
    int b  = blockIdx.x >> 3;
    int oc = (blockIdx.x >> 1) & 3;
    int nc = blockIdx.x & 1;
    __shared__ float trans[64][65];
    int tid = threadIdx.x;
    for (int w = 0; w < 16; ++w) {
        int idx = w * 256 + tid;
        int o_l = idx & 63;
        int n_l = idx >> 6;
        int o = oc * 64 + o_l;
        int n = nc * 64 + n_l;
        int m0 = (b * NPOINT + n) * NS;
        float sc = norm[o], sf = norm[O + o];
        float best = -INFINITY;
#pragma unroll
        for (int k = 0; k < NS; ++k) {
            float v = fmaf(b2f(Y[(size_t)(m0 + k) * O + o]), sc, sf);
            v = v > 0.f ? v : 0.2f * v;
            best = fmaxf(best, gate[m0 + k] * v);
        }
        trans[o_l][n_l] = best;
    }
    __syncthreads();
    for (int w = 0; w < 16; ++w) {
        int idx = w * 256 + tid;
        int o_l = idx >> 6;
        int n_l = idx & 63;
        out[((size_t)b * O + oc * 64 + o_l) * NPOINT + nc * 64 + n_l] = trans[o_l][n_l];
    }
}

// ---------------------------------------------------------------- launch
extern "C" void kernel_launch(void* const* d_in, const int* in_sizes, int n_in,
                              void* d_out, int out_size, void* d_ws, size_t ws_size,
                              hipStream_t stream) {
    const float* xyz = (const float*)d_in[0];
    const float* w1a = (const float*)d_in[1];
    const float* g1a = (const float*)d_in[2];
    const float* b1a = (const float*)d_in[3];
    const float* w1b = (const float*)d_in[4];
    const float* g1b = (const float*)d_in[5];
    const float* b1b = (const float*)d_in[6];
    const float* w2a = (const float*)d_in[7];
    const float* g2a = (const float*)d_in[8];
    const float* b2a = (const float*)d_in[9];
    const float* w2b = (const float*)d_in[10];
    const float* g2b = (const float*)d_in[11];
    const float* b2b = (const float*)d_in[12];

    char* ws = (char*)d_ws;
    constexpr size_t OFF_Q1C   = 0;          // 98304
    constexpr size_t OFF_GATE1 = 98304;      // 524288
    constexpr size_t OFF_Q2C   = 622592;     // 49152
    constexpr size_t OFF_GATE2 = 671744;     // 524288
    constexpr size_t OFF_NORM  = 1196032;    // 8192
    constexpr size_t OFF_W     = 1204224;    // 294912 -> ends 1499136
    constexpr size_t OFF_PS    = 1499136;    // 2097152
    constexpr size_t OFF_PS2   = 3596288;    // 2097152 -> ends 5693440
    constexpr size_t OFF_A     = 5693440;    // 33554432
    constexpr size_t OFF_B     = 39247872;   // 67108864 -> ends 106356736
    constexpr size_t OFF_F1    = OFF_B + 41943040;

    float* q1c   = (float*)(ws + OFF_Q1C);
    float* gate1 = (float*)(ws + OFF_GATE1);
    float* q2c   = (float*)(ws + OFF_Q2C);
    float* gate2 = (float*)(ws + OFF_GATE2);
    float* n1a   = (float*)(ws + OFF_NORM);
    float* n1b   = (float*)(ws + OFF_NORM + 512);
    float* n2a   = (float*)(ws + OFF_NORM + 1536);
    float* n2b   = (float*)(ws + OFF_NORM + 2560);
    short* w1aH  = (short*)(ws + OFF_W);
    short* w1aL  = w1aH + 2048;
    short* w1bH  = w1aL + 2048;
    short* w1bL  = w1bH + 8192;
    short* w2aH  = w1bL + 8192;
    short* w2aL  = w2aH + 20480;
    short* w2bH  = w2aL + 20480;
    short* w2bL  = w2bH + 32768;
    float* pS    = (float*)(ws + OFF_PS);
    float* pS2   = (float*)(ws + OFF_PS2);

    char* A = ws + OFF_A;
    char* B = ws + OFF_B;
    short* X1  = (short*)A;
    short* Y1a = (short*)B;
    short* Y1b = (short*)A;
    short* X2  = (short*)B;
    short* Y2a = (short*)A;
    short* Y2b = (short*)B;
    float* f1  = (float*)(ws + OFF_F1);

    const float r2_1 = (float)(0.15 * 0.15);
    const float r2_2 = (float)(0.3 * 0.3);

    prep_w<<<8,   256, 0, stream>>>(w1a, 64, 6, 32, w1aH, w1aL);
    prep_w<<<32,  256, 0, stream>>>(w1b, 128, 64, 64, w1bH, w1bL);
    prep_w<<<80,  256, 0, stream>>>(w2a, 128, 131, 160, w2aH, w2aL);
    prep_w<<<128, 256, 0, stream>>>(w2b, 256, 128, 128, w2bH, w2bL);

    // ---------------- SA module 1 (N=512 -> 256, ns=16) ----------------
    fps_kernel<512, 256><<<32, 64, 0, stream>>>(xyz, q1c);
    ballq_kernel<512, 256, 16, 3, 32><<<2048, 256, 0, stream>>>(
        xyz, q1c, xyz, r2_1, 0.15f, X1, gate1);
    mfma_conv<32, 64, false><<<CGRID, 256, 0, stream>>>(X1, w1aH, w1aL, nullptr, Y1a, pS, pS2);
    stats_fin<64><<<64, 256, 0, stream>>>(pS, pS2, g1a, b1a, n1a);
    mfma_conv<64, 128, true><<<CGRID, 256, 0, stream>>>(Y1a, w1bH, w1bL, n1a, Y1b, pS, pS2);
    stats_fin<128><<<128, 256, 0, stream>>>(pS, pS2, g1b, b1b, n1b);
    pool1_kernel<16, 256, 128><<<4096, 256, 0, stream>>>(Y1b, n1b, gate1, f1);

    // ---------------- SA module 2 (N=256 -> 128, ns=32) ----------------
    fps_kernel<256, 128><<<32, 64, 0, stream>>>(q1c, q2c);
    ballq_kernel<256, 128, 32, 128, 160><<<1024, 256, 0, stream>>>(
        q1c, q2c, f1, r2_2, 0.3f, X2, gate2);
    mfma_conv<160, 128, false><<<CGRID, 256, 0, stream>>>(X2, w2aH, w2aL, nullptr, Y2a, pS, pS2);
    stats_fin<128><<<128, 256, 0, stream>>>(pS, pS2, g2a, b2a, n2a);
    mfma_conv<128, 256, true><<<CGRID, 256, 0, stream>>>(Y2a, w2bH, w2bL, n2a, Y2b, pS, pS2);
    stats_fin<256><<<256, 256, 0, stream>>>(pS, pS2, g2b, b2b, n2b);
    pool2_kernel<<<256, 256, 0, stream>>>(Y2b, n2b, gate2, (float*)d_out);
}